// Round 1
// 2360.131 us; speedup vs baseline: 1.2079x; 1.2079x over previous
//
#include <hip/hip_runtime.h>
#include <cstdint>
#include <cstddef>

typedef unsigned short u16;
typedef short short8 __attribute__((ext_vector_type(8)));
typedef float f32x4 __attribute__((ext_vector_type(4)));

#define DEV static __device__ __forceinline__

static constexpr int Bn = 4096;
static constexpr int Dn = 1024;
static constexpr int Nn = 16;

// fp32 -> bf16 round-to-nearest-even
DEV u16 f2bf(float f){
  union { float f; unsigned u; } v; v.f = f;
  unsigned u = v.u;
  u += 0x7fffu + ((u >> 16) & 1u);
  return (u16)(u >> 16);
}

DEV void gld_lds16(const void* g, void* l){
  __builtin_amdgcn_global_load_lds(
      (__attribute__((address_space(1))) void*)(g),
      (__attribute__((address_space(3))) void*)(l), 16, 0, 0);
}

// block-wide sums of two values (256 threads = 4 waves)
DEV void block_sum2(float& s0, float& s1, float* red){
  #pragma unroll
  for (int off = 32; off >= 1; off >>= 1){
    s0 += __shfl_xor(s0, off, 64);
    s1 += __shfl_xor(s1, off, 64);
  }
  int wave = threadIdx.x >> 6;
  int lane = threadIdx.x & 63;
  if (lane == 0){ red[wave] = s0; red[4 + wave] = s1; }
  __syncthreads();
  s0 = red[0] + red[1] + red[2] + red[3];
  s1 = red[4] + red[5] + red[6] + red[7];
}

// ---------------------------------------------------------------------------
// Weight transpose + fp32->bf16:  W[K,Nw] -> Wt[Nw,K]
// ---------------------------------------------------------------------------
__global__ __launch_bounds__(256)
void transp_k(const float* __restrict__ W, u16* __restrict__ Wt, int K, int Nw){
  __shared__ u16 tile[32][33];
  int kt = blockIdx.y * 32, nt = blockIdx.x * 32;
  int tr = threadIdx.x >> 5;      // 0..7
  int tc = threadIdx.x & 31;
  #pragma unroll
  for (int i = 0; i < 4; i++){
    int rr = tr + i*8;
    tile[rr][tc] = f2bf(W[(size_t)(kt + rr)*Nw + nt + tc]);
  }
  __syncthreads();
  #pragma unroll
  for (int i = 0; i < 4; i++){
    int rr = tr + i*8;            // local n index
    Wt[(size_t)(nt + rr)*K + kt + tc] = tile[tc][rr];
  }
}

// ---------------------------------------------------------------------------
// Rowwise prep: x_norm = LN(x); h_flat = mean_n(h_memory); pack gi/gm/ri bf16
// ---------------------------------------------------------------------------
__global__ __launch_bounds__(256)
void prep_k(const float* __restrict__ x, const float* __restrict__ hl,
            const float* __restrict__ hm,
            const float* __restrict__ g, const float* __restrict__ bt,
            float* __restrict__ xnorm, u16* __restrict__ gi,
            u16* __restrict__ gm, u16* __restrict__ ri)
{
  __shared__ float red[8];
  int b = blockIdx.x, t = threadIdx.x;
  const float4* xr = (const float4*)(x + (size_t)b*Dn);
  float4 xv = xr[t];
  float xe[4] = {xv.x, xv.y, xv.z, xv.w};
  float s = xe[0]+xe[1]+xe[2]+xe[3];
  float s2 = xe[0]*xe[0]+xe[1]*xe[1]+xe[2]*xe[2]+xe[3]*xe[3];
  block_sum2(s, s2, red);
  float mean = s * (1.f/Dn);
  float inv = rsqrtf(s2*(1.f/Dn) - mean*mean + 1e-5f);
  int d0 = t*4;
  #pragma unroll
  for (int q = 0; q < 4; q++){
    int d = d0 + q;
    size_t i = (size_t)b*Dn + d;
    float xn = (xe[q]-mean)*inv*g[d] + bt[d];
    xnorm[i] = xn;
    gi[(size_t)b*2048 + 1024 + d] = f2bf(xn);
    gi[(size_t)b*2048 + d]        = f2bf(hl[i]);
    gm[(size_t)b*2048 + 1024 + d] = f2bf(xe[q]);
    ri[(size_t)b*3072 + d]        = f2bf(xe[q]);
    const float4* hmr = (const float4*)(hm + i*Nn);
    float4 a0 = hmr[0], a1 = hmr[1], a2 = hmr[2], a3 = hmr[3];
    float hs = a0.x+a0.y+a0.z+a0.w + a1.x+a1.y+a1.z+a1.w
             + a2.x+a2.y+a2.z+a2.w + a3.x+a3.y+a3.z+a3.w;
    gm[(size_t)b*2048 + d] = f2bf(hs * (1.f/16.f));
  }
}

// gi2 = [r*h_logic, x_norm] bf16
__global__ __launch_bounds__(256)
void gi2_k(const float* __restrict__ r, const float* __restrict__ hl,
           const u16* __restrict__ gi, u16* __restrict__ gi2){
  size_t i = (size_t)blockIdx.x*256 + threadIdx.x;   // over B*D
  size_t b = i >> 10, d = i & 1023;
  gi2[b*2048 + d] = f2bf(r[i]*hl[i]);
  gi2[b*2048 + 1024 + d] = gi[b*2048 + 1024 + d];
}

// h_logic_new = (1-z)h + z*h_cand -> out; y_logic = LN(...) -> fp32 + ri
__global__ __launch_bounds__(256)
void logicfin_k(const float* __restrict__ z, const float* __restrict__ hl,
                const float* __restrict__ hc,
                const float* __restrict__ g, const float* __restrict__ bt,
                float* __restrict__ out_hn, float* __restrict__ ylogic,
                u16* __restrict__ ri)
{
  __shared__ float red[8];
  int b = blockIdx.x, t = threadIdx.x;
  int d0 = t*4;
  float hn[4]; float s = 0.f, s2 = 0.f;
  #pragma unroll
  for (int q = 0; q < 4; q++){
    size_t i = (size_t)b*Dn + d0 + q;
    float zz = z[i];
    float v = (1.f - zz)*hl[i] + zz*hc[i];
    hn[q] = v; s += v; s2 += v*v;
    out_hn[i] = v;
  }
  block_sum2(s, s2, red);
  float mean = s*(1.f/Dn);
  float inv = rsqrtf(s2*(1.f/Dn) - mean*mean + 1e-5f);
  #pragma unroll
  for (int q = 0; q < 4; q++){
    int d = d0 + q;
    size_t i = (size_t)b*Dn + d;
    float y = (hn[q]-mean)*inv*g[d] + bt[d];
    ylogic[i] = y;
    ri[(size_t)b*3072 + 1024 + d] = f2bf(y);
  }
}

// y_memory = LN(y_mem + Dp*x) -> fp32 + ri
__global__ __launch_bounds__(256)
void memln_k(const float* __restrict__ ymem, const float* __restrict__ x,
             const float* __restrict__ Dp, const float* __restrict__ g,
             const float* __restrict__ bt, float* __restrict__ ymemory,
             u16* __restrict__ ri)
{
  __shared__ float red[8];
  int b = blockIdx.x, t = threadIdx.x;
  int d0 = t*4;
  float v[4]; float s = 0.f, s2 = 0.f;
  #pragma unroll
  for (int q = 0; q < 4; q++){
    int d = d0 + q;
    size_t i = (size_t)b*Dn + d;
    float tv = ymem[i] + Dp[d]*x[i];
    v[q] = tv; s += tv; s2 += tv*tv;
  }
  block_sum2(s, s2, red);
  float mean = s*(1.f/Dn);
  float inv = rsqrtf(s2*(1.f/Dn) - mean*mean + 1e-5f);
  #pragma unroll
  for (int q = 0; q < 4; q++){
    int d = d0 + q;
    size_t i = (size_t)b*Dn + d;
    float y = (v[q]-mean)*inv*g[d] + bt[d];
    ymemory[i] = y;
    ri[(size_t)b*3072 + 2048 + d] = f2bf(y);
  }
}

// rw = softmax(t1 @ R2 + r2b); y_mixed = rw0*y_logic + rw1*y_memory (bf16)
__global__ __launch_bounds__(256)
void router_k(const float* __restrict__ t1, const float* __restrict__ R2,
              const float* __restrict__ r2b, const float* __restrict__ ylogic,
              const float* __restrict__ ymemory, u16* __restrict__ ymix)
{
  __shared__ float red[8];
  int b = blockIdx.x, t = threadIdx.x;
  int d0 = t*4;
  float s0 = 0.f, s1 = 0.f;
  #pragma unroll
  for (int q = 0; q < 4; q++){
    int d = d0 + q;
    float tv = t1[(size_t)b*Dn + d];
    s0 += tv * R2[2*d];
    s1 += tv * R2[2*d + 1];
  }
  block_sum2(s0, s1, red);
  float l0 = s0 + r2b[0], l1 = s1 + r2b[1];
  float m = fmaxf(l0, l1);
  float e0 = __expf(l0 - m), e1 = __expf(l1 - m);
  float w0 = e0 / (e0 + e1), w1 = e1 / (e0 + e1);
  #pragma unroll
  for (int q = 0; q < 4; q++){
    int d = d0 + q;
    size_t i = (size_t)b*Dn + d;
    ymix[i] = f2bf(w0*ylogic[i] + w1*ymemory[i]);
  }
}

// y_out = LN(preLN) -> fp32; yox = [y_out, x] bf16
__global__ __launch_bounds__(256)
void fusfin_k(const float* __restrict__ pre, const float* __restrict__ x,
              const float* __restrict__ g, const float* __restrict__ bt,
              float* __restrict__ yout, u16* __restrict__ yox)
{
  __shared__ float red[8];
  int b = blockIdx.x, t = threadIdx.x;
  int d0 = t*4;
  float v[4]; float s = 0.f, s2 = 0.f;
  #pragma unroll
  for (int q = 0; q < 4; q++){
    size_t i = (size_t)b*Dn + d0 + q;
    float tv = pre[i];
    v[q] = tv; s += tv; s2 += tv*tv;
  }
  block_sum2(s, s2, red);
  float mean = s*(1.f/Dn);
  float inv = rsqrtf(s2*(1.f/Dn) - mean*mean + 1e-5f);
  #pragma unroll
  for (int q = 0; q < 4; q++){
    int d = d0 + q;
    size_t i = (size_t)b*Dn + d;
    float y = (v[q]-mean)*inv*g[d] + bt[d];
    yout[i] = y;
    yox[(size_t)b*2048 + d] = f2bf(y);
    yox[(size_t)b*2048 + 1024 + d] = f2bf(x[i]);
  }
}

// ---------------------------------------------------------------------------
// MFMA GEMM: C[M,N] = act(A[M,K] @ W^T + bias); 128x128 tile, 2-phase dbuf.
// Grid: dim3(rowTiles=32, colTiles); row tile varies fastest in dispatch
// order; XCD-chunked swizzle gives each XCD a contiguous set of col panels
// so the weight panel stays L2-resident while 32 row-blocks stream over it.
// (nwg is a multiple of 8 for every launch -> swizzle is bijective.)
// act: 0 none, 1 sigmoid, 2 tanh, 3 softplus*0.1, 4 sigmoid*mul (final y)
// ---------------------------------------------------------------------------
__global__ __launch_bounds__(256)
void gemm_k(const u16* __restrict__ A, int K,
            const u16* __restrict__ wt0, const u16* __restrict__ wt1, const u16* __restrict__ wt2,
            const float* __restrict__ bb0, const float* __restrict__ bb1, const float* __restrict__ bb2,
            int n0, int n1, int n2, int act0, int act1, int act2,
            float* __restrict__ c0, float* __restrict__ c1, float* __restrict__ c2,
            const float* __restrict__ mulsrc)
{
  __shared__ u16 As[2][128*32];
  __shared__ u16 Bs[2][128*32];
  const int tid = threadIdx.x;
  const int wave = tid >> 6, lane = tid & 63;
  const int wr = wave >> 1, wc = wave & 1;
  const int rl = lane & 15, quad = lane >> 4;

  int mt, ct;
  {
    int gx = gridDim.x;                    // row tiles (always 32)
    int nwg = gx * gridDim.y;
    int orig = blockIdx.y * gx + blockIdx.x;   // linear dispatch id (x fastest)
    int w = ((orig & 7) * (nwg >> 3)) + (orig >> 3);
    mt = w % gx; ct = w / gx;
  }
  const int m0 = mt * 128;
  const int cb = ct * 128;

  const u16* wt = wt0; const float* bias = bb0; float* cout = c0;
  int ncols = n0, act = act0, cloc = cb;
  if (cb >= n0 + n1){ wt = wt2; bias = bb2; cout = c2; ncols = n2; act = act2; cloc = cb - n0 - n1; }
  else if (cb >= n0){ wt = wt1; bias = bb1; cout = c1; ncols = n1; act = act1; cloc = cb - n0; }

  f32x4 acc[4][4];
  #pragma unroll
  for (int i = 0; i < 4; i++)
    #pragma unroll
    for (int j = 0; j < 4; j++)
      acc[i][j] = (f32x4){0.f, 0.f, 0.f, 0.f};

  const int srow = lane >> 2;          // 0..15 row within a 1KB chunk
  const int skb  = (lane & 3) * 8;     // bf16 element offset within 64B row

  auto STAGE = [&](int k0, int buf){
    #pragma unroll
    for (int i = 0; i < 2; i++){
      int chunk = wave*2 + i;
      int row = chunk*16 + srow;
      gld_lds16(A  + (size_t)(m0   + row)*K + k0 + skb, (char*)As[buf] + chunk*1024);
      gld_lds16(wt + (size_t)(cloc + row)*K + k0 + skb, (char*)Bs[buf] + chunk*1024);
    }
  };

  STAGE(0, 0);
  __syncthreads();                     // drains vmcnt(0): tile 0 ready
  int cur = 0;
  for (int k0 = 0; k0 < K; k0 += 32){
    if (k0 + 32 < K) STAGE(k0 + 32, cur ^ 1);   // prefetch next tile
    short8 af[4], bf[4];
    #pragma unroll
    for (int i = 0; i < 4; i++)
      af[i] = *(const short8*)(&As[cur][(wr*64 + i*16 + rl)*32 + quad*8]);
    #pragma unroll
    for (int j = 0; j < 4; j++)
      bf[j] = *(const short8*)(&Bs[cur][(wc*64 + j*16 + rl)*32 + quad*8]);
    #pragma unroll
    for (int i = 0; i < 4; i++)
      #pragma unroll
      for (int j = 0; j < 4; j++)
        acc[i][j] = __builtin_amdgcn_mfma_f32_16x16x32_bf16(af[i], bf[j], acc[i][j], 0, 0, 0);
    __syncthreads();                   // reads done + prefetch landed
    cur ^= 1;
  }

  #pragma unroll
  for (int j = 0; j < 4; j++){
    int colL = cloc + wc*64 + j*16 + rl;
    float bv = bias[colL];
    #pragma unroll
    for (int i = 0; i < 4; i++){
      f32x4 v = acc[i][j];
      #pragma unroll
      for (int r = 0; r < 4; r++){
        int row = m0 + wr*64 + i*16 + quad*4 + r;
        float val = v[r] + bv;
        if (act == 1) val = 1.f/(1.f + __expf(-val));
        else if (act == 2) val = tanhf(val);
        else if (act == 3) val = (val > 20.f ? val : log1pf(__expf(val))) * 0.1f;
        else if (act == 4) val = (1.f/(1.f + __expf(-val))) * mulsrc[(size_t)row*ncols + colL];
        cout[(size_t)row*ncols + colL] = val;
      }
    }
  }
}

// ---------------------------------------------------------------------------
// Fused WB+WC GEMM + SSM update + y_mem reduce.
// Tile: 128 rows x 64 dn-cols, BOTH weights -> h_new stays in registers,
// eliminating the 268MB h_new round-trip and a second gate-load pass.
// Same per-K-step cost as the unfused kernel: 16KB staged, 8 ds_reads,
// 16 MFMA per wave. Grid dim3(32, 256), same XCD-chunked swizzle.
// ---------------------------------------------------------------------------
__global__ __launch_bounds__(256, 2)
void gemm_bc_k(const u16* __restrict__ A,                 // gm bf16 [B,2048]
               const u16* __restrict__ wtB, const u16* __restrict__ wtC,
               const float* __restrict__ bB, const float* __restrict__ bC,
               const float* __restrict__ alpha, const float* __restrict__ beta,
               const float* __restrict__ delta, const float* __restrict__ xin,
               const float* __restrict__ alog, const float* __restrict__ hmem,
               float* __restrict__ hout, float* __restrict__ ymem)
{
  constexpr int K = 2048;
  __shared__ u16 As[2][128*32];
  __shared__ u16 Bs[2][64*32];
  __shared__ u16 Cs[2][64*32];
  const int tid = threadIdx.x;
  const int wave = tid >> 6, lane = tid & 63;
  const int wr = wave >> 1, wc = wave & 1;
  const int rl = lane & 15, quad = lane >> 4;

  int mt, ct;
  {
    int gx = gridDim.x;                    // 32 row tiles
    int nwg = gx * gridDim.y;              // 8192
    int orig = blockIdx.y * gx + blockIdx.x;
    int w = ((orig & 7) * (nwg >> 3)) + (orig >> 3);
    mt = w % gx; ct = w / gx;
  }
  const int m0 = mt * 128;
  const int cb = ct * 64;

  f32x4 accB[4][2], accC[4][2];
  #pragma unroll
  for (int i = 0; i < 4; i++)
    #pragma unroll
    for (int j = 0; j < 2; j++){
      accB[i][j] = (f32x4){0.f, 0.f, 0.f, 0.f};
      accC[i][j] = (f32x4){0.f, 0.f, 0.f, 0.f};
    }

  const int srow = lane >> 2;
  const int skb  = (lane & 3) * 8;

  auto STAGE = [&](int k0, int buf){
    #pragma unroll
    for (int i = 0; i < 2; i++){
      int chunk = wave*2 + i;
      int row = chunk*16 + srow;
      gld_lds16(A + (size_t)(m0 + row)*K + k0 + skb, (char*)As[buf] + chunk*1024);
    }
    {
      int row = wave*16 + srow;
      gld_lds16(wtB + (size_t)(cb + row)*K + k0 + skb, (char*)Bs[buf] + wave*1024);
      gld_lds16(wtC + (size_t)(cb + row)*K + k0 + skb, (char*)Cs[buf] + wave*1024);
    }
  };

  STAGE(0, 0);
  __syncthreads();
  int cur = 0;
  for (int k0 = 0; k0 < K; k0 += 32){
    if (k0 + 32 < K) STAGE(k0 + 32, cur ^ 1);
    short8 af[4], bf[2], cf[2];
    #pragma unroll
    for (int i = 0; i < 4; i++)
      af[i] = *(const short8*)(&As[cur][(wr*64 + i*16 + rl)*32 + quad*8]);
    #pragma unroll
    for (int j = 0; j < 2; j++){
      bf[j] = *(const short8*)(&Bs[cur][(wc*32 + j*16 + rl)*32 + quad*8]);
      cf[j] = *(const short8*)(&Cs[cur][(wc*32 + j*16 + rl)*32 + quad*8]);
    }
    #pragma unroll
    for (int i = 0; i < 4; i++)
      #pragma unroll
      for (int j = 0; j < 2; j++){
        accB[i][j] = __builtin_amdgcn_mfma_f32_16x16x32_bf16(af[i], bf[j], accB[i][j], 0, 0, 0);
        accC[i][j] = __builtin_amdgcn_mfma_f32_16x16x32_bf16(af[i], cf[j], accC[i][j], 0, 0, 0);
      }
    __syncthreads();
    cur ^= 1;
  }

  // Epilogue: h_new = alpha*exp(delta*A)*h_mem + beta*(delta*Bm)*x, in regs;
  // y_mem[row,d] = sum_n Cm*h_new (shfl-reduce over the 16 rl lanes = n).
  #pragma unroll
  for (int j = 0; j < 2; j++){
    const int dn = cb + wc*32 + j*16 + rl;   // j*16-aligned: rl spans one d
    const int d = dn >> 4;
    const float bvB = bB[dn];
    const float bvC = bC[dn];
    const float Aneg = -__expf(alog[dn]);
    #pragma unroll
    for (int i = 0; i < 4; i++){
      f32x4 vB = accB[i][j];
      f32x4 vC = accC[i][j];
      #pragma unroll
      for (int r = 0; r < 4; r++){
        const int row = m0 + wr*64 + i*16 + quad*4 + r;
        const size_t rd = (size_t)row*Dn + d;
        float Bm = vB[r] + bvB;
        float Cm = vC[r] + bvC;
        float al = alpha[rd];
        float be = beta [rd];
        float de = delta[rd];
        float xv = xin  [rd];
        float hm = hmem[(size_t)row*(Dn*Nn) + dn];
        float hn = al * (__expf(de*Aneg) * hm) + be * (de * Bm * xv);
        hout[(size_t)row*(Dn*Nn) + dn] = hn;
        float p = Cm * hn;
        p += __shfl_xor(p, 1, 64);
        p += __shfl_xor(p, 2, 64);
        p += __shfl_xor(p, 4, 64);
        p += __shfl_xor(p, 8, 64);
        if (rl == 0) ymem[rd] = p;
      }
    }
  }
}

// ---------------------------------------------------------------------------
extern "C" void kernel_launch(void* const* d_in, const int* in_sizes, int n_in,
                              void* d_out, int out_size, void* d_ws, size_t ws_size,
                              hipStream_t stream)
{
  (void)in_sizes; (void)n_in; (void)out_size; (void)ws_size;
  const float* x        = (const float*)d_in[0];
  const float* h_logic  = (const float*)d_in[1];
  const float* h_mem    = (const float*)d_in[2];
  const float* ln_pre_g = (const float*)d_in[3];
  const float* ln_pre_b = (const float*)d_in[4];
  const float* Wz       = (const float*)d_in[5];
  const float* Wr       = (const float*)d_in[6];
  const float* Wh       = (const float*)d_in[7];
  const float* bz       = (const float*)d_in[8];
  const float* br       = (const float*)d_in[9];
  const float* bh       = (const float*)d_in[10];
  const float* ln_lg    = (const float*)d_in[11];
  const float* ln_lb    = (const float*)d_in[12];
  const float* Wa       = (const float*)d_in[13];
  const float* Wb       = (const float*)d_in[14];
  const float* Wd       = (const float*)d_in[15];
  const float* ba       = (const float*)d_in[16];
  const float* bbeta    = (const float*)d_in[17];
  const float* bd       = (const float*)d_in[18];
  const float* A_log    = (const float*)d_in[19];
  const float* WB       = (const float*)d_in[20];
  const float* bB       = (const float*)d_in[21];
  const float* WC       = (const float*)d_in[22];
  const float* bC       = (const float*)d_in[23];
  const float* Dp       = (const float*)d_in[24];
  const float* ln_mg    = (const float*)d_in[25];
  const float* ln_mb    = (const float*)d_in[26];
  const float* R1       = (const float*)d_in[27];
  const float* r1b      = (const float*)d_in[28];
  const float* R2       = (const float*)d_in[29];
  const float* r2b      = (const float*)d_in[30];
  const float* Wout     = (const float*)d_in[31];
  const float* bout     = (const float*)d_in[32];
  const float* ln_fg    = (const float*)d_in[33];
  const float* ln_fb    = (const float*)d_in[34];
  const float* Wg       = (const float*)d_in[35];
  const float* bg       = (const float*)d_in[36];

  float* out_y  = (float*)d_out;
  float* out_hl = out_y + (size_t)Bn*Dn;
  float* out_hm = out_hl + (size_t)Bn*Dn;

  char* ws = (char*)d_ws;
  size_t off = 0;
  auto alloc = [&](size_t bytes)->char*{
    char* p = ws + off; off += (bytes + 255) & ~(size_t)255; return p;
  };
  // bf16 transposed weights
  u16* WzT  = (u16*)alloc((size_t)2048*1024*2);
  u16* WrT  = (u16*)alloc((size_t)2048*1024*2);
  u16* WhT  = (u16*)alloc((size_t)2048*1024*2);
  u16* WaT  = (u16*)alloc((size_t)2048*1024*2);
  u16* WbT  = (u16*)alloc((size_t)2048*1024*2);
  u16* WdT  = (u16*)alloc((size_t)2048*1024*2);
  u16* WgT  = (u16*)alloc((size_t)2048*1024*2);
  u16* WoutT= (u16*)alloc((size_t)1024*1024*2);
  u16* R1T  = (u16*)alloc((size_t)3072*1024*2);
  u16* WBT  = (u16*)alloc((size_t)2048*16384*2);
  u16* WCT  = (u16*)alloc((size_t)2048*16384*2);
  // bf16 activations
  u16* gi   = (u16*)alloc((size_t)Bn*2048*2);
  u16* gm   = (u16*)alloc((size_t)Bn*2048*2);
  u16* gi2  = (u16*)alloc((size_t)Bn*2048*2);
  u16* ri   = (u16*)alloc((size_t)Bn*3072*2);
  u16* ymix = (u16*)alloc((size_t)Bn*1024*2);
  u16* yox  = (u16*)alloc((size_t)Bn*2048*2);
  // fp32 intermediates
  float* xnorm   = (float*)alloc((size_t)Bn*Dn*4);
  float* zb      = (float*)alloc((size_t)Bn*Dn*4);
  float* rb      = (float*)alloc((size_t)Bn*Dn*4);
  float* hcand   = (float*)alloc((size_t)Bn*Dn*4);
  float* alphab  = (float*)alloc((size_t)Bn*Dn*4);
  float* betab   = (float*)alloc((size_t)Bn*Dn*4);
  float* deltab  = (float*)alloc((size_t)Bn*Dn*4);
  float* ylogic  = (float*)alloc((size_t)Bn*Dn*4);
  float* ymemory = (float*)alloc((size_t)Bn*Dn*4);
  float* t1      = (float*)alloc((size_t)Bn*Dn*4);
  float* preLN   = (float*)alloc((size_t)Bn*Dn*4);
  float* yout    = (float*)alloc((size_t)Bn*Dn*4);
  float* ymemb   = (float*)alloc((size_t)Bn*Dn*4);

  auto T = [&](const float* W, u16* Wt, int K, int Nw){
    transp_k<<<dim3(Nw/32, K/32), 256, 0, stream>>>(W, Wt, K, Nw);
  };
  T(Wz, WzT, 2048, 1024);   T(Wr, WrT, 2048, 1024);   T(Wh, WhT, 2048, 1024);
  T(Wa, WaT, 2048, 1024);   T(Wb, WbT, 2048, 1024);   T(Wd, WdT, 2048, 1024);
  T(Wg, WgT, 2048, 1024);   T(Wout, WoutT, 1024, 1024); T(R1, R1T, 3072, 1024);
  T(WB, WBT, 2048, 16384);  T(WC, WCT, 2048, 16384);

  prep_k<<<Bn, 256, 0, stream>>>(x, h_logic, h_mem, ln_pre_g, ln_pre_b,
                                 xnorm, gi, gm, ri);

  // z, r = sigmoid(gi @ {Wz,Wr} + b)
  gemm_k<<<dim3(32, 16), 256, 0, stream>>>(gi, 2048,
      WzT, WrT, WrT, bz, br, br, 1024, 1024, 0, 1, 1, 0,
      zb, rb, rb, nullptr);

  gi2_k<<<dim3((Bn*Dn)/256), 256, 0, stream>>>(rb, h_logic, gi, gi2);

  // h_cand = tanh(gi2 @ Wh + bh)
  gemm_k<<<dim3(32, 8), 256, 0, stream>>>(gi2, 2048,
      WhT, WhT, WhT, bh, bh, bh, 1024, 0, 0, 2, 2, 2,
      hcand, hcand, hcand, nullptr);

  logicfin_k<<<Bn, 256, 0, stream>>>(zb, h_logic, hcand, ln_lg, ln_lb,
                                     out_hl, ylogic, ri);

  // alpha, beta = sigmoid(gm @ {Wa,Wb}); delta = softplus(gm @ Wd)*0.1
  gemm_k<<<dim3(32, 24), 256, 0, stream>>>(gm, 2048,
      WaT, WbT, WdT, ba, bbeta, bd, 1024, 1024, 1024, 1, 1, 3,
      alphab, betab, deltab, nullptr);

  // h_memory_new + y_mem in ONE pass (fused WB/WC GEMM + SSM epilogue)
  gemm_bc_k<<<dim3(32, 256), 256, 0, stream>>>(gm, WBT, WCT, bB, bC,
      alphab, betab, deltab, x, A_log, h_mem, out_hm, ymemb);

  memln_k<<<Bn, 256, 0, stream>>>(ymemb, x, Dp, ln_mg, ln_mb, ymemory, ri);

  // t1 = tanh(ri @ R1 + r1b)
  gemm_k<<<dim3(32, 8), 256, 0, stream>>>(ri, 3072,
      R1T, R1T, R1T, r1b, r1b, r1b, 1024, 0, 0, 2, 2, 2,
      t1, t1, t1, nullptr);

  router_k<<<Bn, 256, 0, stream>>>(t1, R2, r2b, ylogic, ymemory, ymix);

  // preLN = ymix @ Wout + bout
  gemm_k<<<dim3(32, 8), 256, 0, stream>>>(ymix, 1024,
      WoutT, WoutT, WoutT, bout, bout, bout, 1024, 0, 0, 0, 0, 0,
      preLN, preLN, preLN, nullptr);

  fusfin_k<<<Bn, 256, 0, stream>>>(preLN, x, ln_fg, ln_fb, yout, yox);

  // y = sigmoid(yox @ Wg + bg) * y_out -> out slice 0
  gemm_k<<<dim3(32, 8), 256, 0, stream>>>(yox, 2048,
      WgT, WgT, WgT, bg, bg, bg, 1024, 0, 0, 4, 4, 4,
      out_y, out_y, out_y, yout);
}